// Round 11
// baseline (101.317 us; speedup 1.0000x reference)
//
#include <hip/hip_runtime.h>
#include <stdint.h>
#include <math.h>

typedef unsigned long long u64;
typedef unsigned int u32;

#define ENT_CAP  8192       // per-row-block entry capacity (bucketed by k_mask)
#define LDSE_CAP 24576      // LDS-staged entry capacity (96 KB)

// ---------------- kernel 1: extract scores + zero counters ----------------
__global__ void k_scores(const float* __restrict__ dets, float* __restrict__ sc,
                         int* __restrict__ cnt, int n) {
    int i = blockIdx.x * blockDim.x + threadIdx.x;
    if (i < n) sc[i] = dets[i * 5 + 4];
    if (i < 128) cnt[i] = 0;      // 128 per-block counters
}

// ---------------- kernel 2: rank — one wave ranks TWO boxes ----------------
// 4096 waves = 4 waves/SIMD: enough TLP to hide L2 latency (round-9's 4-box at
// 2/SIMD regressed; round-7's 0.5 block/CU LDS version regressed 3x), while
// halving the 256 MB score stream of the 1-box version.
__global__ void k_rank(const float* __restrict__ dets, const float* __restrict__ sc,
                       int* __restrict__ rank,
                       float* __restrict__ sx1, float* __restrict__ sy1,
                       float* __restrict__ sx2, float* __restrict__ sy2,
                       float* __restrict__ sarea, int n) {
    int gid  = blockIdx.x * blockDim.x + threadIdx.x;
    int grp  = gid >> 6;          // group of 2 boxes
    int lane = threadIdx.x & 63;
    int i0 = grp * 2;
    if (i0 >= n) return;

    float s0 = sc[i0];
    float s1 = (i0 + 1 < n) ? sc[i0 + 1] : 0.0f;

    int c0 = 0, c1 = 0;
    int n4 = n >> 2;
    const float4* sc4 = (const float4*)sc;
    for (int j4 = lane; j4 < n4; j4 += 64) {
        float4 v = sc4[j4];
        int j = j4 * 4;
        c0 += (v.x > s0) || (v.x == s0 && (j + 0) < i0);
        c0 += (v.y > s0) || (v.y == s0 && (j + 1) < i0);
        c0 += (v.z > s0) || (v.z == s0 && (j + 2) < i0);
        c0 += (v.w > s0) || (v.w == s0 && (j + 3) < i0);
        c1 += (v.x > s1) || (v.x == s1 && (j + 0) < i0 + 1);
        c1 += (v.y > s1) || (v.y == s1 && (j + 1) < i0 + 1);
        c1 += (v.z > s1) || (v.z == s1 && (j + 2) < i0 + 1);
        c1 += (v.w > s1) || (v.w == s1 && (j + 3) < i0 + 1);
    }
    for (int j = (n4 << 2) + lane; j < n; j += 64) {   // tail (n%4 != 0)
        float sj = sc[j];
        c0 += (sj > s0) || (sj == s0 && j < i0);
        c1 += (sj > s1) || (sj == s1 && j < i0 + 1);
    }
    #pragma unroll
    for (int off = 32; off > 0; off >>= 1) {
        c0 += __shfl_xor(c0, off, 64);
        c1 += __shfl_xor(c1, off, 64);
    }
    if (lane < 2) {
        int i = i0 + lane;
        if (i < n) {
            int r = lane ? c1 : c0;
            rank[i] = r;
            float x1 = dets[i * 5 + 0], y1 = dets[i * 5 + 1];
            float x2 = dets[i * 5 + 2], y2 = dets[i * 5 + 3];
            sx1[r] = x1; sy1[r] = y1; sx2[r] = x2; sy2[r] = y2;
            sarea[r] = (x2 - x1 + 1.0f) * (y2 - y1 + 1.0f);
        }
    }
}

// ---------------- kernel 3: sparse suppression graph (triangular grid) ----------------
// ent2[by][.] : (k<<16 | j) entries, bucketed per row-block by atomic counter.
__global__ void k_mask(const float* __restrict__ sx1, const float* __restrict__ sy1,
                       const float* __restrict__ sx2, const float* __restrict__ sy2,
                       const float* __restrict__ sarea, const float* __restrict__ thrp,
                       u64* __restrict__ diag, u64* __restrict__ nzarr,
                       u32* __restrict__ ent2, int* __restrict__ cnt, int n, int nw) {
    int t = blockIdx.x;
    // decode upper-triangular (by, bx), row-major: row by has (nw-by) blocks
    double nn = (double)nw + 0.5;
    int by = (int)(nn - sqrt(nn * nn - 2.0 * (double)t));
    if (by < 0) by = 0; if (by > nw - 1) by = nw - 1;
    while (by + 1 <= nw - 1 && ((by + 1) * nw - ((by + 1) * by) / 2) <= t) ++by;
    while ((by * nw - (by * (by - 1)) / 2) > t) --by;
    int bx = by + (t - (by * nw - (by * (by - 1)) / 2));

    int k  = threadIdx.x;                // 0..63
    int i  = by * 64 + k;                // global row

    __shared__ float cx1[64], cy1[64], cx2[64], cy2[64], ca[64];
    int j0 = bx * 64;
    cx1[k] = sx1[j0 + k]; cy1[k] = sy1[j0 + k];
    cx2[k] = sx2[j0 + k]; cy2[k] = sy2[j0 + k];
    ca[k]  = sarea[j0 + k];
    __syncthreads();

    float x1 = sx1[i], y1 = sy1[i], x2 = sx2[i], y2 = sy2[i], ar = sarea[i];
    float thr = *thrp;
    u64 word = 0ULL;
    // mul-compare replaces IEEE div: inter/denom > thr <=> inter > thr*denom
    // (denom >= 1 always). absmax==0 held for two rounds with this.
    #pragma unroll 8
    for (int jj = 0; jj < 64; ++jj) {
        float xx1 = fmaxf(x1, cx1[jj]);
        float yy1 = fmaxf(y1, cy1[jj]);
        float xx2 = fminf(x2, cx2[jj]);
        float yy2 = fminf(y2, cy2[jj]);
        float w = fmaxf(xx2 - xx1 + 1.0f, 0.0f);
        float h = fmaxf(yy2 - yy1 + 1.0f, 0.0f);
        float inter = w * h;
        float denom = ar + ca[jj] - inter;
        word |= ((u64)(inter > thr * denom)) << jj;
    }

    if (bx == by) {
        word &= ~((2ULL << k) - 1ULL);   // keep only j > i
        diag[i] = word;
        u64 bal = __ballot(word != 0ULL);
        if (k == 0) nzarr[by] = bal;     // free nz summary for k_scan
        return;
    }
    if (__ballot(word != 0ULL) == 0ULL) return;   // whole block conflict-free
    int pc = __popcll(word);
    if (pc) {
        int base2 = atomicAdd(&cnt[by], pc);
        u64 ww = word;
        int x = 0;
        while (ww) {
            int jj = __builtin_ctzll(ww); ww &= ww - 1;
            int j = j0 + jj;
            if (base2 + x < ENT_CAP)
                ent2[(size_t)by * ENT_CAP + base2 + x] = ((u32)k << 16) | (u32)j;
            ++x;
        }
    }
}

// ---------------- helper: readlane of a u64 (uniform runtime lane index) ----------------
__device__ __forceinline__ u64 readlane_u64(u64 v, int lane) {
    unsigned lo = (unsigned)__builtin_amdgcn_readlane((int)(v & 0xffffffffu), lane);
    unsigned hi = (unsigned)__builtin_amdgcn_readlane((int)(v >> 32), lane);
    return ((u64)hi << 32) | lo;
}

// ---------------- kernel 4: sparse greedy scan — single wave ----------------
// Staging: segment-copy from the already-bucketed ent2 (8 independent masked
// loads in flight, plain ds_write — NO per-entry cursor atomics).
// Hot loop: pure-register skip test; LDS-only when active; global diag reads
// only on the rare in-block-conflict resolve path.
__launch_bounds__(64, 1)
__global__ void k_scan(const u64* __restrict__ diag, const u64* __restrict__ nzarr,
                       const u32* __restrict__ ent2, const int* __restrict__ cnt,
                       u64* __restrict__ remv, int n, int nw) {
    extern __shared__ char smem[];
    u64* lds_remv = (u64*)smem;                 // 128 u64
    u32* lds_ent  = (u32*)(smem + 1024);        // LDSE_CAP u32

    int lane = threadIdx.x;
    lds_remv[lane] = 0ULL;
    lds_remv[64 + lane] = 0ULL;

    int c0 = cnt[lane];
    int c1 = cnt[64 + lane];
    c0 = (c0 < ENT_CAP) ? c0 : ENT_CAP;
    c1 = (c1 < ENT_CAP) ? c1 : ENT_CAP;
    u64 nz0 = (lane < nw)      ? nzarr[lane]      : 0ULL;
    u64 nz1 = (64 + lane < nw) ? nzarr[64 + lane] : 0ULL;

    // exclusive prefix offsets over 128 counts (wave-parallel scan, no memory)
    int s0 = c0;
    #pragma unroll
    for (int d = 1; d < 64; d <<= 1) { int tv = __shfl_up(s0, d, 64); if (lane >= d) s0 += tv; }
    int tot0 = __builtin_amdgcn_readlane(s0, 63);
    int s1 = c1;
    #pragma unroll
    for (int d = 1; d < 64; d <<= 1) { int tv = __shfl_up(s1, d, 64); if (lane >= d) s1 += tv; }
    int tot1 = __builtin_amdgcn_readlane(s1, 63);
    int o0 = s0 - c0;
    int o1 = tot0 + s1 - c1;
    int S  = tot0 + tot1;

    bool fast = (S <= LDSE_CAP);

    if (fast) {
        // segment-copy staging: 8 segments per group, loads independent
        for (int g = 0; g < nw; g += 8) {
            u32 a[8]; int cbs[8], obs[8];
            #pragma unroll
            for (int u = 0; u < 8; ++u) {
                int b = g + u;
                bool lo = b < 64; int sel = b & 63;
                cbs[u] = (b < nw) ? __builtin_amdgcn_readlane(lo ? c0 : c1, sel) : 0;
                obs[u] = (b < nw) ? __builtin_amdgcn_readlane(lo ? o0 : o1, sel) : 0;
                a[u] = (lane < cbs[u]) ? ent2[(size_t)b * ENT_CAP + lane] : 0u;
            }
            #pragma unroll
            for (int u = 0; u < 8; ++u)
                if (lane < cbs[u]) lds_ent[obs[u] + lane] = a[u];
            // overflow rounds for cb > 64 (rare)
            for (int u = 0; u < 8; ++u)
                for (int idx = 64 + lane; idx < cbs[u]; idx += 64)
                    lds_ent[obs[u] + idx] = ent2[(size_t)(g + u) * ENT_CAP + idx];
        }
    }

    for (int b = 0; b < nw; ++b) {
        int sel = b & 63; bool lo = b < 64;
        int cb  = __builtin_amdgcn_readlane(lo ? c0 : c1, sel);
        u64 nzb = readlane_u64(lo ? nz0 : nz1, sel);
        if ((nzb | (u64)(u32)cb) == 0ULL) continue;     // pure-register skip

        u64 w = lds_remv[b];               // sees all prior atomicOrs (same wave, in-order LDS)
        if (nzb & ~w) {
            u64 avail = ~w & nzb;
            while (avail) {                // ascending greedy over alive conflicting rows
                int k = __builtin_ctzll(avail);
                w |= diag[(size_t)b * 64 + k];          // uniform L2 load — rare path
                avail &= ~(w | (1ULL << k));
            }
            if (lane == 0) lds_remv[b] = w;
        }
        int ob = __builtin_amdgcn_readlane(lo ? o0 : o1, sel);
        if (fast) {
            for (int idx = lane; idx < cb; idx += 64) {
                u32 e = lds_ent[ob + idx];
                int k = e >> 16, j = e & 0xffff;
                if (!((w >> k) & 1ULL)) atomicOr(&lds_remv[j >> 6], 1ULL << (j & 63));
            }
        } else {
            for (int idx = lane; idx < cb; idx += 64) {
                u32 e = ent2[(size_t)b * ENT_CAP + idx];
                int k = e >> 16, j = e & 0xffff;
                if (!((w >> k) & 1ULL)) atomicOr(&lds_remv[j >> 6], 1ULL << (j & 63));
            }
        }
    }

    if (lane < nw) remv[lane] = lds_remv[lane];
    if (64 + lane < nw) remv[64 + lane] = lds_remv[64 + lane];
}

// ---------------- kernel 5: write output ----------------
__global__ void k_out(const float* __restrict__ dets, const int* __restrict__ rank,
                      const u64* __restrict__ remv, float* __restrict__ out, int n) {
    int idx = blockIdx.x * blockDim.x + threadIdx.x;
    if (idx >= n * 5) return;
    int i = idx / 5;
    int r = rank[i];
    u64 w = remv[r >> 6];
    float keep = ((w >> (r & 63)) & 1ULL) ? 0.0f : 1.0f;
    out[idx] = dets[idx] * keep;
}

extern "C" void kernel_launch(void* const* d_in, const int* in_sizes, int n_in,
                              void* d_out, int out_size, void* d_ws, size_t ws_size,
                              hipStream_t stream) {
    const float* dets = (const float*)d_in[0];
    const float* thrp = (const float*)d_in[1];
    int n  = in_sizes[0] / 5;
    int nw = (n + 63) / 64;

    char* ws = (char*)d_ws;
    size_t off = 0;
    auto carve = [&](size_t bytes) { char* p = ws + off; off = (off + bytes + 255) & ~(size_t)255; return p; };
    u64* diag  = (u64*)carve((size_t)n * sizeof(u64));
    u64* nzarr = (u64*)carve(128 * sizeof(u64));
    u32* ent2  = (u32*)carve((size_t)128 * ENT_CAP * sizeof(u32));
    int* cnt   = (int*)carve(128 * sizeof(int));
    float* sc    = (float*)carve((size_t)n * sizeof(float));
    int*   rank  = (int*)  carve((size_t)n * sizeof(int));
    float* sx1   = (float*)carve((size_t)n * sizeof(float));
    float* sy1   = (float*)carve((size_t)n * sizeof(float));
    float* sx2   = (float*)carve((size_t)n * sizeof(float));
    float* sy2   = (float*)carve((size_t)n * sizeof(float));
    float* sarea = (float*)carve((size_t)n * sizeof(float));
    u64* remv    = (u64*)  carve((size_t)nw * sizeof(u64));

    float* out = (float*)d_out;

    int tri = nw * (nw + 1) / 2;
    int scan_lds = 1024 + LDSE_CAP * 4;
    int ngrp = (n + 1) / 2;                       // 2 boxes per wave in k_rank

    k_scores<<<(n + 255) / 256, 256, 0, stream>>>(dets, sc, cnt, n);
    k_rank<<<(ngrp * 64 + 255) / 256, 256, 0, stream>>>(dets, sc, rank, sx1, sy1, sx2, sy2, sarea, n);
    k_mask<<<tri, 64, 0, stream>>>(sx1, sy1, sx2, sy2, sarea, thrp, diag, nzarr, ent2, cnt, n, nw);
    k_scan<<<1, 64, scan_lds, stream>>>(diag, nzarr, ent2, cnt, remv, n, nw);
    k_out<<<(n * 5 + 255) / 256, 256, 0, stream>>>(dets, rank, remv, out, n);
}

// Round 12
// 85.256 us; speedup vs baseline: 1.1884x; 1.1884x over previous
//
#include <hip/hip_runtime.h>
#include <stdint.h>
#include <math.h>

typedef unsigned long long u64;
typedef unsigned int u32;

#define ENT_CAP  8192       // per-row-block capacity (fallback layout only)
#define GCAP     65536      // compact global entry capacity
#define LDSE_CAP 24576      // LDS-staged entry capacity (96 KB)

// ---------------- kernel 1: extract scores + zero counters ----------------
__global__ void k_scores(const float* __restrict__ dets, float* __restrict__ sc,
                         int* __restrict__ cnt, int n) {
    int i = blockIdx.x * blockDim.x + threadIdx.x;
    if (i < n) sc[i] = dets[i * 5 + 4];
    if (i < 129) cnt[i] = 0;      // 128 per-block counters + 1 global total
}

// ---------------- kernel 2: rank — one wave ranks TWO boxes ----------------
// 4096 waves = 4 waves/SIMD: enough TLP to hide L2 latency (4-box at 2/SIMD
// regressed; LDS-staged 1-block/CU regressed 3x), half the 1-box L2 traffic.
__global__ void k_rank(const float* __restrict__ dets, const float* __restrict__ sc,
                       int* __restrict__ rank,
                       float* __restrict__ sx1, float* __restrict__ sy1,
                       float* __restrict__ sx2, float* __restrict__ sy2,
                       float* __restrict__ sarea, int n) {
    int gid  = blockIdx.x * blockDim.x + threadIdx.x;
    int grp  = gid >> 6;          // group of 2 boxes
    int lane = threadIdx.x & 63;
    int i0 = grp * 2;
    if (i0 >= n) return;

    float s0 = sc[i0];
    float s1 = (i0 + 1 < n) ? sc[i0 + 1] : 0.0f;

    int c0 = 0, c1 = 0;
    int n4 = n >> 2;
    const float4* sc4 = (const float4*)sc;
    for (int j4 = lane; j4 < n4; j4 += 64) {
        float4 v = sc4[j4];
        int j = j4 * 4;
        c0 += (v.x > s0) || (v.x == s0 && (j + 0) < i0);
        c0 += (v.y > s0) || (v.y == s0 && (j + 1) < i0);
        c0 += (v.z > s0) || (v.z == s0 && (j + 2) < i0);
        c0 += (v.w > s0) || (v.w == s0 && (j + 3) < i0);
        c1 += (v.x > s1) || (v.x == s1 && (j + 0) < i0 + 1);
        c1 += (v.y > s1) || (v.y == s1 && (j + 1) < i0 + 1);
        c1 += (v.z > s1) || (v.z == s1 && (j + 2) < i0 + 1);
        c1 += (v.w > s1) || (v.w == s1 && (j + 3) < i0 + 1);
    }
    for (int j = (n4 << 2) + lane; j < n; j += 64) {   // tail (n%4 != 0)
        float sj = sc[j];
        c0 += (sj > s0) || (sj == s0 && j < i0);
        c1 += (sj > s1) || (sj == s1 && j < i0 + 1);
    }
    #pragma unroll
    for (int off = 32; off > 0; off >>= 1) {
        c0 += __shfl_xor(c0, off, 64);
        c1 += __shfl_xor(c1, off, 64);
    }
    if (lane < 2) {
        int i = i0 + lane;
        if (i < n) {
            int r = lane ? c1 : c0;
            rank[i] = r;
            float x1 = dets[i * 5 + 0], y1 = dets[i * 5 + 1];
            float x2 = dets[i * 5 + 2], y2 = dets[i * 5 + 3];
            sx1[r] = x1; sy1[r] = y1; sx2[r] = x2; sy2[r] = y2;
            sarea[r] = (x2 - x1 + 1.0f) * (y2 - y1 + 1.0f);
        }
    }
}

// ---------------- kernel 3: sparse suppression graph (triangular grid) ----------------
__global__ void k_mask(const float* __restrict__ sx1, const float* __restrict__ sy1,
                       const float* __restrict__ sx2, const float* __restrict__ sy2,
                       const float* __restrict__ sarea, const float* __restrict__ thrp,
                       u64* __restrict__ diag, u64* __restrict__ nzarr,
                       u32* __restrict__ entc, u32* __restrict__ ent2,
                       int* __restrict__ cnt, int n, int nw) {
    int t = blockIdx.x;
    // decode upper-triangular (by, bx), row-major: row by has (nw-by) blocks
    double nn = (double)nw + 0.5;
    int by = (int)(nn - sqrt(nn * nn - 2.0 * (double)t));
    if (by < 0) by = 0; if (by > nw - 1) by = nw - 1;
    while (by + 1 <= nw - 1 && ((by + 1) * nw - ((by + 1) * by) / 2) <= t) ++by;
    while ((by * nw - (by * (by - 1)) / 2) > t) --by;
    int bx = by + (t - (by * nw - (by * (by - 1)) / 2));

    int k  = threadIdx.x;                // 0..63
    int i  = by * 64 + k;                // global row

    __shared__ float cx1[64], cy1[64], cx2[64], cy2[64], ca[64];
    int j0 = bx * 64;
    cx1[k] = sx1[j0 + k]; cy1[k] = sy1[j0 + k];
    cx2[k] = sx2[j0 + k]; cy2[k] = sy2[j0 + k];
    ca[k]  = sarea[j0 + k];
    __syncthreads();

    float x1 = sx1[i], y1 = sy1[i], x2 = sx2[i], y2 = sy2[i], ar = sarea[i];
    float thr = *thrp;
    u64 word = 0ULL;
    // mul-compare replaces IEEE div: inter/denom > thr <=> inter > thr*denom
    // (denom >= 1 always). absmax==0 held for two rounds with this.
    #pragma unroll 8
    for (int jj = 0; jj < 64; ++jj) {
        float xx1 = fmaxf(x1, cx1[jj]);
        float yy1 = fmaxf(y1, cy1[jj]);
        float xx2 = fminf(x2, cx2[jj]);
        float yy2 = fminf(y2, cy2[jj]);
        float w = fmaxf(xx2 - xx1 + 1.0f, 0.0f);
        float h = fmaxf(yy2 - yy1 + 1.0f, 0.0f);
        float inter = w * h;
        float denom = ar + ca[jj] - inter;
        word |= ((u64)(inter > thr * denom)) << jj;
    }

    if (bx == by) {
        word &= ~((2ULL << k) - 1ULL);   // keep only j > i
        diag[i] = word;
        u64 bal = __ballot(word != 0ULL);
        if (k == 0) nzarr[by] = bal;     // free nz summary for k_scan
        return;
    }
    if (__ballot(word != 0ULL) == 0ULL) return;   // whole block conflict-free
    int pc = __popcll(word);
    if (pc) {
        int base2 = atomicAdd(&cnt[by], pc);       // per-block (fallback layout)
        int baseg = atomicAdd(&cnt[128], pc);      // compact global array
        u64 ww = word;
        int x = 0;
        while (ww) {
            int jj = __builtin_ctzll(ww); ww &= ww - 1;
            int j = j0 + jj;
            if (base2 + x < ENT_CAP)
                ent2[(size_t)by * ENT_CAP + base2 + x] = ((u32)k << 16) | (u32)j;
            if (n <= 8192 && baseg + x < GCAP)
                entc[baseg + x] = ((u32)by << 19) | ((u32)k << 13) | (u32)j;
            ++x;
        }
    }
}

// ---------------- helper: readlane of a u64 (uniform runtime lane index) ----------------
__device__ __forceinline__ u64 readlane_u64(u64 v, int lane) {
    unsigned lo = (unsigned)__builtin_amdgcn_readlane((int)(v & 0xffffffffu), lane);
    unsigned hi = (unsigned)__builtin_amdgcn_readlane((int)(v >> 32), lane);
    return ((u64)hi << 32) | lo;
}

// ---------------- kernel 4: sparse greedy scan — single wave, NO globals in hot loop ----------------
// Staging: contiguous uint4 loads of the compact entc array (the ONLY staging
// pattern this compiler pipelines) + LDS-cursor atomic bucketing (~40cy LDS).
// Round-10's segment-copy (divergent masked loads) serialized at ~500cy each.
__launch_bounds__(64, 1)
__global__ void k_scan(const u64* __restrict__ diag, const u64* __restrict__ nzarr,
                       const u32* __restrict__ entc, const u32* __restrict__ ent2,
                       const int* __restrict__ cnt, u64* __restrict__ remv,
                       int n, int nw) {
    extern __shared__ char smem[];
    u64* lds_remv = (u64*)smem;                 // 128 u64
    int* lds_cur  = (int*)(smem + 1024);        // 128 int
    u32* lds_ent  = (u32*)(smem + 1536);        // LDSE_CAP u32

    int lane = threadIdx.x;
    lds_remv[lane] = 0ULL;
    lds_remv[64 + lane] = 0ULL;

    int c0 = cnt[lane];
    int c1 = cnt[64 + lane];
    int S  = cnt[128];
    u64 nz0 = (lane < nw)      ? nzarr[lane]      : 0ULL;
    u64 nz1 = (64 + lane < nw) ? nzarr[64 + lane] : 0ULL;

    // exclusive prefix offsets over 128 counts (wave-parallel scan, no memory)
    int s0 = c0;
    #pragma unroll
    for (int d = 1; d < 64; d <<= 1) { int tv = __shfl_up(s0, d, 64); if (lane >= d) s0 += tv; }
    int tot0 = __builtin_amdgcn_readlane(s0, 63);
    int s1 = c1;
    #pragma unroll
    for (int d = 1; d < 64; d <<= 1) { int tv = __shfl_up(s1, d, 64); if (lane >= d) s1 += tv; }
    int o0 = s0 - c0;
    int o1 = tot0 + s1 - c1;

    bool fast = (S <= LDSE_CAP) && (n <= 8192);

    if (fast) {
        lds_cur[lane] = o0;
        lds_cur[64 + lane] = o1;
        // stage all S compact entries into LDS, bucketed by block
        for (int g0 = 0; g0 < S; g0 += 1024) {
            int base = g0 + lane * 16;
            uint4 v0 = *(const uint4*)(entc + base);
            uint4 v1 = *(const uint4*)(entc + base + 4);
            uint4 v2 = *(const uint4*)(entc + base + 8);
            uint4 v3 = *(const uint4*)(entc + base + 12);
            u32 ee[16] = { v0.x, v0.y, v0.z, v0.w, v1.x, v1.y, v1.z, v1.w,
                           v2.x, v2.y, v2.z, v2.w, v3.x, v3.y, v3.z, v3.w };
            #pragma unroll
            for (int u = 0; u < 16; ++u) {
                if (base + u < S) {
                    u32 e = ee[u];
                    int b = e >> 19;
                    int pos = atomicAdd(&lds_cur[b], 1);
                    lds_ent[pos] = e;
                }
            }
        }
    }

    for (int b = 0; b < nw; ++b) {
        int sel = b & 63;
        int cb  = __builtin_amdgcn_readlane((b < 64) ? c0 : c1, sel);
        u64 nzb = readlane_u64((b < 64) ? nz0 : nz1, sel);
        if ((nzb | (u64)(u32)cb) == 0ULL) continue;     // pure-register skip

        u64 w = lds_remv[b];               // sees all prior atomicOrs (same wave, in-order LDS)
        if (nzb & ~w) {
            u64 avail = ~w & nzb;
            while (avail) {                // ascending greedy over alive conflicting rows
                int k = __builtin_ctzll(avail);
                w |= diag[(size_t)b * 64 + k];          // uniform L2 load — rare path
                avail &= ~(w | (1ULL << k));
            }
            if (lane == 0) lds_remv[b] = w;
        }
        int ob = __builtin_amdgcn_readlane((b < 64) ? o0 : o1, sel);
        if (fast) {
            for (int idx = lane; idx < cb; idx += 64) {
                u32 e = lds_ent[ob + idx];
                int k = (e >> 13) & 63, j = e & 8191;
                if (!((w >> k) & 1ULL)) atomicOr(&lds_remv[j >> 6], 1ULL << (j & 63));
            }
        } else {
            int cbl = (cb < ENT_CAP) ? cb : ENT_CAP;
            for (int idx = lane; idx < cbl; idx += 64) {
                u32 e = ent2[(size_t)b * ENT_CAP + idx];
                int k = e >> 16, j = e & 0xffff;
                if (!((w >> k) & 1ULL)) atomicOr(&lds_remv[j >> 6], 1ULL << (j & 63));
            }
        }
    }

    if (lane < nw) remv[lane] = lds_remv[lane];
    if (64 + lane < nw) remv[64 + lane] = lds_remv[64 + lane];
}

// ---------------- kernel 5: write output ----------------
__global__ void k_out(const float* __restrict__ dets, const int* __restrict__ rank,
                      const u64* __restrict__ remv, float* __restrict__ out, int n) {
    int idx = blockIdx.x * blockDim.x + threadIdx.x;
    if (idx >= n * 5) return;
    int i = idx / 5;
    int r = rank[i];
    u64 w = remv[r >> 6];
    float keep = ((w >> (r & 63)) & 1ULL) ? 0.0f : 1.0f;
    out[idx] = dets[idx] * keep;
}

extern "C" void kernel_launch(void* const* d_in, const int* in_sizes, int n_in,
                              void* d_out, int out_size, void* d_ws, size_t ws_size,
                              hipStream_t stream) {
    const float* dets = (const float*)d_in[0];
    const float* thrp = (const float*)d_in[1];
    int n  = in_sizes[0] / 5;
    int nw = (n + 63) / 64;

    char* ws = (char*)d_ws;
    size_t off = 0;
    auto carve = [&](size_t bytes) { char* p = ws + off; off = (off + bytes + 255) & ~(size_t)255; return p; };
    u64* diag  = (u64*)carve((size_t)n * sizeof(u64));
    u64* nzarr = (u64*)carve(128 * sizeof(u64));
    u32* entc  = (u32*)carve((size_t)GCAP * sizeof(u32));
    u32* ent2  = (u32*)carve((size_t)128 * ENT_CAP * sizeof(u32));
    int* cnt   = (int*)carve(129 * sizeof(int));
    float* sc    = (float*)carve((size_t)n * sizeof(float));
    int*   rank  = (int*)  carve((size_t)n * sizeof(int));
    float* sx1   = (float*)carve((size_t)n * sizeof(float));
    float* sy1   = (float*)carve((size_t)n * sizeof(float));
    float* sx2   = (float*)carve((size_t)n * sizeof(float));
    float* sy2   = (float*)carve((size_t)n * sizeof(float));
    float* sarea = (float*)carve((size_t)n * sizeof(float));
    u64* remv    = (u64*)  carve((size_t)nw * sizeof(u64));

    float* out = (float*)d_out;

    int tri = nw * (nw + 1) / 2;
    int scan_lds = 1024 + 512 + LDSE_CAP * 4;
    int ngrp = (n + 1) / 2;                       // 2 boxes per wave in k_rank

    k_scores<<<(n + 255) / 256, 256, 0, stream>>>(dets, sc, cnt, n);
    k_rank<<<(ngrp * 64 + 255) / 256, 256, 0, stream>>>(dets, sc, rank, sx1, sy1, sx2, sy2, sarea, n);
    k_mask<<<tri, 64, 0, stream>>>(sx1, sy1, sx2, sy2, sarea, thrp, diag, nzarr, entc, ent2, cnt, n, nw);
    k_scan<<<1, 64, scan_lds, stream>>>(diag, nzarr, entc, ent2, cnt, remv, n, nw);
    k_out<<<(n * 5 + 255) / 256, 256, 0, stream>>>(dets, rank, remv, out, n);
}

// Round 13
// 83.656 us; speedup vs baseline: 1.2111x; 1.0191x over previous
//
#include <hip/hip_runtime.h>
#include <stdint.h>
#include <math.h>

typedef unsigned long long u64;
typedef unsigned int u32;

#define ENT_CAP  8192       // per-row-block capacity (fallback layout only)
#define GCAP     65536      // compact global entry capacity
#define LDSE_CAP 16384      // LDS-staged entry capacity (64 KB)

// ---------------- kernel 1: extract scores + zero counters ----------------
__global__ void k_scores(const float* __restrict__ dets, float* __restrict__ sc,
                         int* __restrict__ cnt, int n) {
    int i = blockIdx.x * blockDim.x + threadIdx.x;
    if (i < n) sc[i] = dets[i * 5 + 4];
    if (i < 129) cnt[i] = 0;      // 128 per-block counters + 1 global total
}

// ---------------- kernel 2: rank — one wave ranks TWO boxes ----------------
// 4096 waves = 4 waves/SIMD: enough TLP to hide L2 latency (4-box at 2/SIMD
// regressed; LDS-staged 1-block/CU regressed 3x), half the 1-box L2 traffic.
__global__ void k_rank(const float* __restrict__ dets, const float* __restrict__ sc,
                       int* __restrict__ rank,
                       float* __restrict__ sx1, float* __restrict__ sy1,
                       float* __restrict__ sx2, float* __restrict__ sy2,
                       float* __restrict__ sarea, int n) {
    int gid  = blockIdx.x * blockDim.x + threadIdx.x;
    int grp  = gid >> 6;          // group of 2 boxes
    int lane = threadIdx.x & 63;
    int i0 = grp * 2;
    if (i0 >= n) return;

    float s0 = sc[i0];
    float s1 = (i0 + 1 < n) ? sc[i0 + 1] : 0.0f;

    int c0 = 0, c1 = 0;
    int n4 = n >> 2;
    const float4* sc4 = (const float4*)sc;
    for (int j4 = lane; j4 < n4; j4 += 64) {
        float4 v = sc4[j4];
        int j = j4 * 4;
        c0 += (v.x > s0) || (v.x == s0 && (j + 0) < i0);
        c0 += (v.y > s0) || (v.y == s0 && (j + 1) < i0);
        c0 += (v.z > s0) || (v.z == s0 && (j + 2) < i0);
        c0 += (v.w > s0) || (v.w == s0 && (j + 3) < i0);
        c1 += (v.x > s1) || (v.x == s1 && (j + 0) < i0 + 1);
        c1 += (v.y > s1) || (v.y == s1 && (j + 1) < i0 + 1);
        c1 += (v.z > s1) || (v.z == s1 && (j + 2) < i0 + 1);
        c1 += (v.w > s1) || (v.w == s1 && (j + 3) < i0 + 1);
    }
    for (int j = (n4 << 2) + lane; j < n; j += 64) {   // tail (n%4 != 0)
        float sj = sc[j];
        c0 += (sj > s0) || (sj == s0 && j < i0);
        c1 += (sj > s1) || (sj == s1 && j < i0 + 1);
    }
    #pragma unroll
    for (int off = 32; off > 0; off >>= 1) {
        c0 += __shfl_xor(c0, off, 64);
        c1 += __shfl_xor(c1, off, 64);
    }
    if (lane < 2) {
        int i = i0 + lane;
        if (i < n) {
            int r = lane ? c1 : c0;
            rank[i] = r;
            float x1 = dets[i * 5 + 0], y1 = dets[i * 5 + 1];
            float x2 = dets[i * 5 + 2], y2 = dets[i * 5 + 3];
            sx1[r] = x1; sy1[r] = y1; sx2[r] = x2; sy2[r] = y2;
            sarea[r] = (x2 - x1 + 1.0f) * (y2 - y1 + 1.0f);
        }
    }
}

// ---------------- kernel 3: sparse suppression graph (triangular grid) ----------------
__global__ void k_mask(const float* __restrict__ sx1, const float* __restrict__ sy1,
                       const float* __restrict__ sx2, const float* __restrict__ sy2,
                       const float* __restrict__ sarea, const float* __restrict__ thrp,
                       u64* __restrict__ diag, u64* __restrict__ nzarr,
                       u32* __restrict__ entc, u32* __restrict__ ent2,
                       int* __restrict__ cnt, int n, int nw) {
    int t = blockIdx.x;
    // decode upper-triangular (by, bx), row-major: row by has (nw-by) blocks
    double nn = (double)nw + 0.5;
    int by = (int)(nn - sqrt(nn * nn - 2.0 * (double)t));
    if (by < 0) by = 0; if (by > nw - 1) by = nw - 1;
    while (by + 1 <= nw - 1 && ((by + 1) * nw - ((by + 1) * by) / 2) <= t) ++by;
    while ((by * nw - (by * (by - 1)) / 2) > t) --by;
    int bx = by + (t - (by * nw - (by * (by - 1)) / 2));

    int k  = threadIdx.x;                // 0..63
    int i  = by * 64 + k;                // global row

    __shared__ float cx1[64], cy1[64], cx2[64], cy2[64], ca[64];
    int j0 = bx * 64;
    cx1[k] = sx1[j0 + k]; cy1[k] = sy1[j0 + k];
    cx2[k] = sx2[j0 + k]; cy2[k] = sy2[j0 + k];
    ca[k]  = sarea[j0 + k];
    __syncthreads();

    float x1 = sx1[i], y1 = sy1[i], x2 = sx2[i], y2 = sy2[i], ar = sarea[i];
    float thr = *thrp;
    u64 word = 0ULL;
    // mul-compare replaces IEEE div: inter/denom > thr <=> inter > thr*denom
    // (denom >= 1 always). absmax==0 held for three rounds with this.
    #pragma unroll 8
    for (int jj = 0; jj < 64; ++jj) {
        float xx1 = fmaxf(x1, cx1[jj]);
        float yy1 = fmaxf(y1, cy1[jj]);
        float xx2 = fminf(x2, cx2[jj]);
        float yy2 = fminf(y2, cy2[jj]);
        float w = fmaxf(xx2 - xx1 + 1.0f, 0.0f);
        float h = fmaxf(yy2 - yy1 + 1.0f, 0.0f);
        float inter = w * h;
        float denom = ar + ca[jj] - inter;
        word |= ((u64)(inter > thr * denom)) << jj;
    }

    if (bx == by) {
        word &= ~((2ULL << k) - 1ULL);   // keep only j > i
        diag[i] = word;
        u64 bal = __ballot(word != 0ULL);
        if (k == 0) nzarr[by] = bal;     // free nz summary for k_scan
        return;
    }
    if (__ballot(word != 0ULL) == 0ULL) return;   // whole block conflict-free
    int pc = __popcll(word);
    if (pc) {
        int base2 = atomicAdd(&cnt[by], pc);       // per-block (fallback layout)
        int baseg = atomicAdd(&cnt[128], pc);      // compact global array
        u64 ww = word;
        int x = 0;
        while (ww) {
            int jj = __builtin_ctzll(ww); ww &= ww - 1;
            int j = j0 + jj;
            if (base2 + x < ENT_CAP)
                ent2[(size_t)by * ENT_CAP + base2 + x] = ((u32)k << 16) | (u32)j;
            if (n <= 8192 && baseg + x < GCAP)
                entc[baseg + x] = ((u32)by << 19) | ((u32)k << 13) | (u32)j;
            ++x;
        }
    }
}

// ---------------- helper: readlane of a u64 (uniform runtime lane index) ----------------
__device__ __forceinline__ u64 readlane_u64(u64 v, int lane) {
    unsigned lo = (unsigned)__builtin_amdgcn_readlane((int)(v & 0xffffffffu), lane);
    unsigned hi = (unsigned)__builtin_amdgcn_readlane((int)(v >> 32), lane);
    return ((u64)hi << 32) | lo;
}

// ---------------- kernel 4: sparse greedy scan — single wave, ALL-LDS hot loop ----------------
// Staging (the one pattern this compiler pipelines: contiguous unconditional
// vector loads): compact entc -> LDS-cursor bucketing, and the whole diag
// array -> LDS (so the rare-but-serial resolve path never touches global).
// Hot loop: entry read issued BEFORE the remv read (both LDS trips overlap).
__launch_bounds__(64, 1)
__global__ void k_scan(const u64* __restrict__ diag, const u64* __restrict__ nzarr,
                       const u32* __restrict__ entc, const u32* __restrict__ ent2,
                       const int* __restrict__ cnt, u64* __restrict__ remv,
                       int n, int nw) {
    extern __shared__ char smem[];
    u64* lds_remv = (u64*)smem;                 // 128 u64   (1 KB)
    int* lds_cur  = (int*)(smem + 1024);        // 128 int   (0.5 KB)
    u32* lds_ent  = (u32*)(smem + 1536);        // LDSE_CAP u32 (64 KB)
    u64* lds_diag = (u64*)(smem + 1536 + LDSE_CAP * 4);   // n u64 (64 KB @ n=8192)

    int lane = threadIdx.x;
    lds_remv[lane] = 0ULL;
    lds_remv[64 + lane] = 0ULL;

    int c0 = cnt[lane];
    int c1 = cnt[64 + lane];
    int S  = cnt[128];
    u64 nz0 = (lane < nw)      ? nzarr[lane]      : 0ULL;
    u64 nz1 = (64 + lane < nw) ? nzarr[64 + lane] : 0ULL;

    // exclusive prefix offsets over 128 counts (wave-parallel scan, no memory)
    int s0 = c0;
    #pragma unroll
    for (int d = 1; d < 64; d <<= 1) { int tv = __shfl_up(s0, d, 64); if (lane >= d) s0 += tv; }
    int tot0 = __builtin_amdgcn_readlane(s0, 63);
    int s1 = c1;
    #pragma unroll
    for (int d = 1; d < 64; d <<= 1) { int tv = __shfl_up(s1, d, 64); if (lane >= d) s1 += tv; }
    int o0 = s0 - c0;
    int o1 = tot0 + s1 - c1;

    bool fast = (S <= LDSE_CAP) && (n <= 8192);

    // ---- bulk-stage diag into LDS: contiguous uint4 loads, fully pipelined ----
    {
        const uint4* dg4 = (const uint4*)diag;
        uint4* ld4 = (uint4*)lds_diag;
        int nq = n >> 1;                       // n u64 = n/2 uint4
        #pragma unroll 4
        for (int q = lane; q < nq; q += 64)
            ld4[q] = dg4[q];
    }

    if (fast) {
        lds_cur[lane] = o0;
        lds_cur[64 + lane] = o1;
        // stage all S compact entries into LDS, bucketed by block
        for (int g0 = 0; g0 < S; g0 += 1024) {
            int base = g0 + lane * 16;
            uint4 v0 = *(const uint4*)(entc + base);
            uint4 v1 = *(const uint4*)(entc + base + 4);
            uint4 v2 = *(const uint4*)(entc + base + 8);
            uint4 v3 = *(const uint4*)(entc + base + 12);
            u32 ee[16] = { v0.x, v0.y, v0.z, v0.w, v1.x, v1.y, v1.z, v1.w,
                           v2.x, v2.y, v2.z, v2.w, v3.x, v3.y, v3.z, v3.w };
            #pragma unroll
            for (int u = 0; u < 16; ++u) {
                if (base + u < S) {
                    u32 e = ee[u];
                    int b = e >> 19;
                    int pos = atomicAdd(&lds_cur[b], 1);
                    lds_ent[pos] = e;
                }
            }
        }
    }

    for (int b = 0; b < nw; ++b) {
        int sel = b & 63;
        int cb  = __builtin_amdgcn_readlane((b < 64) ? c0 : c1, sel);
        u64 nzb = readlane_u64((b < 64) ? nz0 : nz1, sel);
        if ((nzb | (u64)(u32)cb) == 0ULL) continue;     // pure-register skip

        int ob = __builtin_amdgcn_readlane((b < 64) ? o0 : o1, sel);
        // issue first-round entry read BEFORE the remv read: both LDS trips
        // overlap (in-order LDS completion; atomicOr waits on both at once)
        u32 e0 = 0;
        bool have0 = fast && (lane < cb);
        if (have0) e0 = lds_ent[ob + lane];

        u64 w = lds_remv[b];               // sees all prior atomicOrs (same wave)
        if (nzb & ~w) {
            u64 avail = ~w & nzb;
            while (avail) {                // ascending greedy over alive conflicting rows
                int k = __builtin_ctzll(avail);
                w |= lds_diag[b * 64 + k];              // LDS, not global
                avail &= ~(w | (1ULL << k));
            }
            if (lane == 0) lds_remv[b] = w;
        }
        if (fast) {
            if (have0) {
                int k = (e0 >> 13) & 63, j = e0 & 8191;
                if (!((w >> k) & 1ULL)) atomicOr(&lds_remv[j >> 6], 1ULL << (j & 63));
            }
            for (int idx = 64 + lane; idx < cb; idx += 64) {    // rare heavy blocks
                u32 e = lds_ent[ob + idx];
                int k = (e >> 13) & 63, j = e & 8191;
                if (!((w >> k) & 1ULL)) atomicOr(&lds_remv[j >> 6], 1ULL << (j & 63));
            }
        } else {
            int cbl = (cb < ENT_CAP) ? cb : ENT_CAP;
            for (int idx = lane; idx < cbl; idx += 64) {
                u32 e = ent2[(size_t)b * ENT_CAP + idx];
                int k = e >> 16, j = e & 0xffff;
                if (!((w >> k) & 1ULL)) atomicOr(&lds_remv[j >> 6], 1ULL << (j & 63));
            }
        }
    }

    if (lane < nw) remv[lane] = lds_remv[lane];
    if (64 + lane < nw) remv[64 + lane] = lds_remv[64 + lane];
}

// ---------------- kernel 5: write output ----------------
__global__ void k_out(const float* __restrict__ dets, const int* __restrict__ rank,
                      const u64* __restrict__ remv, float* __restrict__ out, int n) {
    int idx = blockIdx.x * blockDim.x + threadIdx.x;
    if (idx >= n * 5) return;
    int i = idx / 5;
    int r = rank[i];
    u64 w = remv[r >> 6];
    float keep = ((w >> (r & 63)) & 1ULL) ? 0.0f : 1.0f;
    out[idx] = dets[idx] * keep;
}

extern "C" void kernel_launch(void* const* d_in, const int* in_sizes, int n_in,
                              void* d_out, int out_size, void* d_ws, size_t ws_size,
                              hipStream_t stream) {
    const float* dets = (const float*)d_in[0];
    const float* thrp = (const float*)d_in[1];
    int n  = in_sizes[0] / 5;
    int nw = (n + 63) / 64;

    char* ws = (char*)d_ws;
    size_t off = 0;
    auto carve = [&](size_t bytes) { char* p = ws + off; off = (off + bytes + 255) & ~(size_t)255; return p; };
    u64* diag  = (u64*)carve((size_t)n * sizeof(u64));
    u64* nzarr = (u64*)carve(128 * sizeof(u64));
    u32* entc  = (u32*)carve((size_t)GCAP * sizeof(u32));
    u32* ent2  = (u32*)carve((size_t)128 * ENT_CAP * sizeof(u32));
    int* cnt   = (int*)carve(129 * sizeof(int));
    float* sc    = (float*)carve((size_t)n * sizeof(float));
    int*   rank  = (int*)  carve((size_t)n * sizeof(int));
    float* sx1   = (float*)carve((size_t)n * sizeof(float));
    float* sy1   = (float*)carve((size_t)n * sizeof(float));
    float* sx2   = (float*)carve((size_t)n * sizeof(float));
    float* sy2   = (float*)carve((size_t)n * sizeof(float));
    float* sarea = (float*)carve((size_t)n * sizeof(float));
    u64* remv    = (u64*)  carve((size_t)nw * sizeof(u64));

    float* out = (float*)d_out;

    int tri = nw * (nw + 1) / 2;
    int scan_lds = 1024 + 512 + LDSE_CAP * 4 + n * 8;   // 129.5 KB @ n=8192 (<160 KB/CU)
    int ngrp = (n + 1) / 2;                       // 2 boxes per wave in k_rank

    k_scores<<<(n + 255) / 256, 256, 0, stream>>>(dets, sc, cnt, n);
    k_rank<<<(ngrp * 64 + 255) / 256, 256, 0, stream>>>(dets, sc, rank, sx1, sy1, sx2, sy2, sarea, n);
    k_mask<<<tri, 64, 0, stream>>>(sx1, sy1, sx2, sy2, sarea, thrp, diag, nzarr, entc, ent2, cnt, n, nw);
    k_scan<<<1, 64, scan_lds, stream>>>(diag, nzarr, entc, ent2, cnt, remv, n, nw);
    k_out<<<(n * 5 + 255) / 256, 256, 0, stream>>>(dets, rank, remv, out, n);
}